// Round 5
// baseline (700.190 us; speedup 1.0000x reference)
//
#include <hip/hip_runtime.h>
#include <hip/hip_bf16.h>

#define NC      80
#define BATCH   1048576
#define CHUNKS  (BATCH / 32)           // 32768 K-chunks of 32 rows
#define NTHR    256
#define LDSW    17                     // dword stride per class row (odd -> bank spread)
#define WAVE_LDS (NC * LDSW)           // 1360 dwords per wave
#define NTILE   15                     // upper-triangle 16x16 tiles of 80x80

using bf16x8 = __attribute__((ext_vector_type(8))) __bf16;
using f32x4  = __attribute__((ext_vector_type(4))) float;

// G = label^T @ label, bf16 MFMA, templated on grid size (NB blocks).
// NB=1024: the real producer (R3-identical). NB=128: DIAGNOSTIC probe run
// into scratch -- long enough (~250+us) to surface in rocprof top-5 with
// FETCH_SIZE / VALUBusy / VGPR_Count, which gram has never shown.
template <int NB>
__global__ __launch_bounds__(NTHR) void gram_kernel(const float* __restrict__ label,
                                                    float* __restrict__ G) {
    constexpr int CPW_ = CHUNKS / (NB * 4);     // contiguous chunks per wave
    __shared__ unsigned int Lt[4 * WAVE_LDS];   // 21760 B wave-private staging
    __shared__ float Gs[NC * NC];               // 25600 B block accumulator

    const int tid  = threadIdx.x;
    const int lane = tid & 63;
    const int wv   = tid >> 6;
    const int m    = lane & 15;
    const int quad = lane >> 4;
    unsigned int* lt = Lt + wv * WAVE_LDS;

    for (int u = tid; u < NC * NC; u += NTHR) Gs[u] = 0.0f;
    __syncthreads();

    int rp_[5], c4_[5];
#pragma unroll
    for (int i = 0; i < 5; ++i) {
        int p  = i * 64 + lane;
        rp_[i] = p / 20;
        c4_[i] = p % 20;
    }

    const int wid = blockIdx.x * 4 + wv;
    const float* span = label + (size_t)wid * CPW_ * (32 * NC);

    f32x4 acc[NTILE];
#pragma unroll
    for (int t = 0; t < NTILE; ++t) acc[t] = (f32x4){0.f, 0.f, 0.f, 0.f};

    auto LOAD = [&](float4* A, float4* B, int c) {
        const float* cb = span + (size_t)c * (32 * NC);
#pragma unroll
        for (int i = 0; i < 5; ++i) {
            const float* pa = cb + (2 * rp_[i]) * NC + 4 * c4_[i];
            A[i] = *(const float4*)pa;         // row 2rp   (k even)
            B[i] = *(const float4*)(pa + NC);  // row 2rp+1 (k odd)
        }
    };

    auto PROC = [&](const float4* A, const float4* B) {
#pragma unroll
        for (int i = 0; i < 5; ++i) {
            unsigned int p0 = (__float_as_uint(B[i].x) & 0xFFFF0000u) | (__float_as_uint(A[i].x) >> 16);
            unsigned int p1 = (__float_as_uint(B[i].y) & 0xFFFF0000u) | (__float_as_uint(A[i].y) >> 16);
            unsigned int p2 = (__float_as_uint(B[i].z) & 0xFFFF0000u) | (__float_as_uint(A[i].z) >> 16);
            unsigned int p3 = (__float_as_uint(B[i].w) & 0xFFFF0000u) | (__float_as_uint(A[i].w) >> 16);
            unsigned int base = (unsigned)(4 * c4_[i]) * LDSW + rp_[i];
            lt[base]            = p0;
            lt[base + LDSW]     = p1;
            lt[base + 2 * LDSW] = p2;
            lt[base + 3 * LDSW] = p3;
        }
        bf16x8 frag[5];
#pragma unroll
        for (int t = 0; t < 5; ++t) {
            const unsigned int* fp = lt + (unsigned)(16 * t + m) * LDSW + quad * 4;
            union { unsigned int u[4]; bf16x8 b; } cv;
            cv.u[0] = fp[0]; cv.u[1] = fp[1]; cv.u[2] = fp[2]; cv.u[3] = fp[3];
            frag[t] = cv.b;
        }
        int idx = 0;
#pragma unroll
        for (int ti = 0; ti < 5; ++ti)
#pragma unroll
            for (int tj = ti; tj < 5; ++tj) {
                acc[idx] = __builtin_amdgcn_mfma_f32_16x16x32_bf16(
                    frag[ti], frag[tj], acc[idx], 0, 0, 0);
                ++idx;
            }
    };

    float4 A0[5], B0[5], A1[5], B1[5];
    LOAD(A0, B0, 0);
    LOAD(A1, B1, 1);
    for (int c = 0; c + 3 < CPW_; c += 2) {
        PROC(A0, B0); LOAD(A0, B0, c + 2);
        PROC(A1, B1); LOAD(A1, B1, c + 3);
    }
    PROC(A0, B0);
    PROC(A1, B1);

    {
        int idx = 0;
#pragma unroll
        for (int ti = 0; ti < 5; ++ti)
#pragma unroll
            for (int tj = ti; tj < 5; ++tj) {
#pragma unroll
                for (int r = 0; r < 4; ++r) {
                    atomicAdd(&Gs[(16 * ti + quad * 4 + r) * NC + 16 * tj + m],
                              acc[idx][r]);
                }
                ++idx;
            }
    }
    __syncthreads();

    {
        const int r  = tid >> 4;
        const int cl = tid & 15;
#pragma unroll
        for (int ti = 0; ti < 5; ++ti)
#pragma unroll
            for (int tj = ti; tj < 5; ++tj) {
                int row = 16 * ti + r, col = 16 * tj + cl;
                atomicAdd(&G[row * NC + col], Gs[row * NC + col]);
            }
    }
}

// DIAGNOSTIC 2: babel-style pure-read ceiling probe. Max TLP (tiny VGPR,
// 32 waves/CU), device-wide contiguous front (idx = gid + k*stride),
// 335 MB from L3-cold poisoned d_ws. Duration recovered from dur_us delta.
#define RB_BLOCKS 2048
#define RB_N4     20971520                      // 335.5 MB of float4
__global__ __launch_bounds__(256) void readbw_kernel(const float4* __restrict__ src,
                                                     float* __restrict__ sink) {
    const int gid = blockIdx.x * 256 + threadIdx.x;
    const int stride = RB_BLOCKS * 256;
    float s = 0.f;
    for (int k = 0; k < RB_N4 / (RB_BLOCKS * 256); ++k) {
        float4 v = src[(size_t)k * stride + gid];
        s += v.x + v.y + v.z + v.w;
    }
    sink[gid] = s;   // defeat DCE; 2 MB write, negligible
}

// Stage 2: target = cooc/(count+eps) + eye ; smooth-L1-ish ; mean -> out[0]
__global__ __launch_bounds__(256) void loss_kernel(const float* __restrict__ pre_adj,
                                                   const float* __restrict__ G,
                                                   float* __restrict__ out) {
    const int tid = threadIdx.x;
    float sum = 0.f;
    for (int u = tid; u < NC * NC; u += 256) {
        int i = u / NC, j = u - i * NC;
        float target;
        if (i == j) {
            target = 1.0f;
        } else {
            float num = ((i >> 4) <= (j >> 4)) ? G[i * NC + j] : G[j * NC + i];
            float cnt = G[i * NC + i];
            target = num / (cnt + 1e-7f);
        }
        float r = fabsf(pre_adj[u] - target);
        sum += (r < 1.0f) ? r * r : (r - 0.5f);
    }
#pragma unroll
    for (int off = 32; off > 0; off >>= 1) sum += __shfl_down(sum, off);
    __shared__ float ws[4];
    if ((tid & 63) == 0) ws[tid >> 6] = sum;
    __syncthreads();
    if (tid == 0) out[0] = (ws[0] + ws[1] + ws[2] + ws[3]) * (1.0f / 6400.0f);
}

extern "C" void kernel_launch(void* const* d_in, const int* in_sizes, int n_in,
                              void* d_out, int out_size, void* d_ws, size_t ws_size,
                              hipStream_t stream) {
    const float* pre_adj = (const float*)d_in[0];   // [80,80]
    const float* label   = (const float*)d_in[1];   // [1048576,80]
    float* out = (float*)d_out;                     // scalar

    char* ws = (char*)d_ws;
    float*  G        = (float*)ws;                          // real accumulator
    float4* rb_src   = (float4*)(ws + (size_t)16  * 1024 * 1024);  // 335 MB read region
    float*  rb_sink  = (float*) (ws + (size_t)360 * 1024 * 1024);  // 2 MB sink
    float*  Gscratch = (float*) (ws + (size_t)400 * 1024 * 1024);  // probe output (ignored)

    hipMemsetAsync(G, 0, NC * NC * sizeof(float), stream);
    // Probe A: pure-read ceiling (L3-cold poison data, contiguous front)
    readbw_kernel<<<RB_BLOCKS, 256, 0, stream>>>(rb_src, rb_sink);
    // Probe B: gram at 1/8 grid -> ~250+us -> surfaces in rocprof top-5
    gram_kernel<128><<<128, NTHR, 0, stream>>>(label, Gscratch);
    // Real computation (R3-identical):
    gram_kernel<1024><<<1024, NTHR, 0, stream>>>(label, G);
    loss_kernel<<<1, 256, 0, stream>>>(pre_adj, G, out);
}

// Round 6
// 524.337 us; speedup vs baseline: 1.3354x; 1.3354x over previous
//
#include <hip/hip_runtime.h>
#include <hip/hip_bf16.h>

#define NC      80
#define BATCH   1048576
#define CHUNKS  (BATCH / 32)           // 32768 K-chunks of 32 rows
#define NTHR    256
#define NBLK    1024
#define NWAVES  (NBLK * NTHR / 64)     // 4096 waves
#define CPW     (CHUNKS / NWAVES)      // 8 chunks per wave (grid-strided)
#define LDSW    17                     // dword stride per class row (odd -> bank spread)
#define WAVE_LDS (NC * LDSW)           // 1360 dwords per wave
#define NTILE   15                     // upper-triangle 16x16 tiles of 80x80

using bf16x8 = __attribute__((ext_vector_type(8))) __bf16;
using f32x4  = __attribute__((ext_vector_type(4))) float;

// Stage 1: G = label^T @ label (upper-triangle 16x16 tiles), bf16 MFMA.
// Labels in {0,1} -> bf16 truncation exact; partial sums are integers < 2^24
// -> fp32 accumulation (incl. atomicAdd) exact and order-independent.
//
// v5: COMPACT-FRONT chunk assignment. R2-R5 gave each wave a private
// contiguous span; measured result: ~2.7 TB/s regardless of grid size
// (129us @1024 blocks ~= ~110us @128 blocks), while a coherent-front reader
// (readbw probe, R5) and the harness fill move the same bytes at ~6.5 TB/s.
// Theory: thousands of disjoint streams thrash HBM row buffers; a
// time-compact front keeps same-channel requests address-adjacent.
// Here wave wid reads chunks wid + k*NWAVES: at iteration k the whole
// device's bursts fall in one contiguous 40 MB window.
__global__ __launch_bounds__(NTHR) void gram_kernel(const float* __restrict__ label,
                                                    float* __restrict__ G) {
    __shared__ unsigned int Lt[4 * WAVE_LDS];   // 21760 B wave-private staging
    __shared__ float Gs[NC * NC];               // 25600 B block accumulator

    const int tid  = threadIdx.x;
    const int lane = tid & 63;
    const int wv   = tid >> 6;
    const int m    = lane & 15;   // class-within-tile (frag row)
    const int quad = lane >> 4;   // k-subchunk selector
    unsigned int* lt = Lt + wv * WAVE_LDS;

    for (int u = tid; u < NC * NC; u += NTHR) Gs[u] = 0.0f;
    __syncthreads();   // Gs zeros visible before any epilogue atomics

    // loop-invariant per-lane load/store decomposition
    int rp_[5], c4_[5];
#pragma unroll
    for (int i = 0; i < 5; ++i) {
        int p  = i * 64 + lane;    // float4-pair unit index, 0..319
        rp_[i] = p / 20;           // row-pair 0..15
        c4_[i] = p % 20;           // float4-within-row 0..19
    }

    const int wid = blockIdx.x * 4 + wv;

    f32x4 acc[NTILE];
#pragma unroll
    for (int t = 0; t < NTILE; ++t) acc[t] = (f32x4){0.f, 0.f, 0.f, 0.f};

    // issue one chunk's 10 coalesced dwordx4 loads (rows 2rp & 2rp+1)
    auto LOAD = [&](float4* A, float4* B, int c) {
        const float* cb = label + (size_t)c * (32 * NC);
#pragma unroll
        for (int i = 0; i < 5; ++i) {
            const float* pa = cb + (2 * rp_[i]) * NC + 4 * c4_[i];
            A[i] = *(const float4*)pa;         // row 2rp   (k even)
            B[i] = *(const float4*)(pa + NC);  // row 2rp+1 (k odd)
        }
    };

    // pack to bf16 k-pairs -> wave-private transposed LDS -> frags -> 15 MFMAs
    auto PROC = [&](const float4* A, const float4* B) {
#pragma unroll
        for (int i = 0; i < 5; ++i) {
            unsigned int p0 = (__float_as_uint(B[i].x) & 0xFFFF0000u) | (__float_as_uint(A[i].x) >> 16);
            unsigned int p1 = (__float_as_uint(B[i].y) & 0xFFFF0000u) | (__float_as_uint(A[i].y) >> 16);
            unsigned int p2 = (__float_as_uint(B[i].z) & 0xFFFF0000u) | (__float_as_uint(A[i].z) >> 16);
            unsigned int p3 = (__float_as_uint(B[i].w) & 0xFFFF0000u) | (__float_as_uint(A[i].w) >> 16);
            unsigned int base = (unsigned)(4 * c4_[i]) * LDSW + rp_[i];
            lt[base]            = p0;
            lt[base + LDSW]     = p1;
            lt[base + 2 * LDSW] = p2;
            lt[base + 3 * LDSW] = p3;
        }
        bf16x8 frag[5];
#pragma unroll
        for (int t = 0; t < 5; ++t) {
            // class = 16t+m, k-pairs quad*4..quad*4+3; bank = (17m+4q)&31 -> 2-way max
            const unsigned int* fp = lt + (unsigned)(16 * t + m) * LDSW + quad * 4;
            union { unsigned int u[4]; bf16x8 b; } cv;
            cv.u[0] = fp[0]; cv.u[1] = fp[1]; cv.u[2] = fp[2]; cv.u[3] = fp[3];
            frag[t] = cv.b;
        }
        int idx = 0;
#pragma unroll
        for (int ti = 0; ti < 5; ++ti)
#pragma unroll
            for (int tj = ti; tj < 5; ++tj) {
                acc[idx] = __builtin_amdgcn_mfma_f32_16x16x32_bf16(
                    frag[ti], frag[tj], acc[idx], 0, 0, 0);
                ++idx;
            }
    };

    // grid-strided chunks, depth-2 register prefetch
    float4 A0[5], B0[5], A1[5], B1[5];
    LOAD(A0, B0, wid);
    LOAD(A1, B1, wid + NWAVES);
#pragma unroll
    for (int i = 0; i < 3; ++i) {
        PROC(A0, B0); LOAD(A0, B0, wid + (2 * i + 2) * NWAVES);
        PROC(A1, B1); LOAD(A1, B1, wid + (2 * i + 3) * NWAVES);
    }
    PROC(A0, B0);
    PROC(A1, B1);

    // wave accs -> Gs (C/D layout: col = lane&15, row = quad*4 + reg)
    {
        int idx = 0;
#pragma unroll
        for (int ti = 0; ti < 5; ++ti)
#pragma unroll
            for (int tj = ti; tj < 5; ++tj) {
#pragma unroll
                for (int r = 0; r < 4; ++r) {
                    atomicAdd(&Gs[(16 * ti + quad * 4 + r) * NC + 16 * tj + m],
                              acc[idx][r]);
                }
                ++idx;
            }
    }
    __syncthreads();

    // block partial -> global G (upper-triangle tiles; 15 atomics/thread)
    {
        const int r  = tid >> 4;
        const int cl = tid & 15;
#pragma unroll
        for (int ti = 0; ti < 5; ++ti)
#pragma unroll
            for (int tj = ti; tj < 5; ++tj) {
                int row = 16 * ti + r, col = 16 * tj + cl;
                atomicAdd(&G[row * NC + col], Gs[row * NC + col]);
            }
    }
}

// Stage 2: target = cooc/(count+eps) + eye ; smooth-L1-ish ; mean -> out[0]
__global__ __launch_bounds__(256) void loss_kernel(const float* __restrict__ pre_adj,
                                                   const float* __restrict__ G,
                                                   float* __restrict__ out) {
    const int tid = threadIdx.x;
    float sum = 0.f;
    for (int u = tid; u < NC * NC; u += 256) {
        int i = u / NC, j = u - i * NC;
        float target;
        if (i == j) {
            target = 1.0f;
        } else {
            // G stored only for tile(i) <= tile(j); G is symmetric
            float num = ((i >> 4) <= (j >> 4)) ? G[i * NC + j] : G[j * NC + i];
            float cnt = G[i * NC + i];   // count[i] = diag (binary labels)
            target = num / (cnt + 1e-7f);
        }
        float r = fabsf(pre_adj[u] - target);
        sum += (r < 1.0f) ? r * r : (r - 0.5f);
    }
#pragma unroll
    for (int off = 32; off > 0; off >>= 1) sum += __shfl_down(sum, off);
    __shared__ float ws[4];
    if ((tid & 63) == 0) ws[tid >> 6] = sum;
    __syncthreads();
    if (tid == 0) out[0] = (ws[0] + ws[1] + ws[2] + ws[3]) * (1.0f / 6400.0f);
}

extern "C" void kernel_launch(void* const* d_in, const int* in_sizes, int n_in,
                              void* d_out, int out_size, void* d_ws, size_t ws_size,
                              hipStream_t stream) {
    const float* pre_adj = (const float*)d_in[0];   // [80,80]
    const float* label   = (const float*)d_in[1];   // [1048576,80]
    float* out = (float*)d_out;                     // scalar
    float* G   = (float*)d_ws;                      // 6400 f32 accumulator

    hipMemsetAsync(G, 0, NC * NC * sizeof(float), stream);
    gram_kernel<<<NBLK, NTHR, 0, stream>>>(label, G);
    loss_kernel<<<1, 256, 0, stream>>>(pre_adj, G, out);
}